// Round 1
// baseline (112.211 us; speedup 1.0000x reference)
//
#include <hip/hip_runtime.h>
#include <math.h>

#define NN 8192
#define EPSF 1e-6f

// ws layout:
//   pack[NN]  : float4 {T[j], exp(Pr[j]), E[j]*exp(Ps[j]), 0}   (131072 B)
//   sumR[NN]  : float                                            (32768 B)
//   sumS[NN]  : float                                            (32768 B)
// total 196608 B

// Kernel A: precompute packed per-j data, zero the partial-sum arrays
// (ws is re-poisoned 0xAA before every call, so zeroing must happen here).
__global__ __launch_bounds__(256) void ds_prep(
    const float* __restrict__ Pr, const float* __restrict__ Ps,
    const float* __restrict__ T,  const int* __restrict__ E,
    float4* __restrict__ pack, float* __restrict__ sumR, float* __restrict__ sumS) {
  int i = blockIdx.x * 256 + threadIdx.x;
  float t  = T[i];
  float er = __expf(Pr[i]);
  float es = __expf(Ps[i]) * (E[i] ? 1.0f : 0.0f);
  pack[i] = make_float4(t, er, es, 0.0f);
  sumR[i] = 0.0f;
  sumS[i] = 0.0f;
}

// Kernel B: 2-D grid. blockIdx.x picks a 256-row slab (thread = row),
// blockIdx.y picks a 1024-wide j-chunk. j is wave-uniform -> scalar loads.
#define ROWS_PER_BLOCK 256
#define J_CHUNK 1024
__global__ __launch_bounds__(256) void ds_main(
    const float* __restrict__ T, const float4* __restrict__ pack,
    float* __restrict__ sumR, float* __restrict__ sumS) {
  int i  = blockIdx.x * ROWS_PER_BLOCK + threadIdx.x;
  int j0 = blockIdx.y * J_CHUNK;
  float Ti = T[i];
  float sr = 0.0f, ss = 0.0f;
#pragma unroll 8
  for (int j = j0; j < j0 + J_CHUNK; ++j) {
    float4 p = pack[j];               // wave-uniform address -> s_load
    sr += (p.x > Ti) ? p.y : 0.0f;    // risk set: T[j] > T[i]
    ss += (p.x < Ti) ? p.z : 0.0f;    // surv set: T[j] < T[i] && E[j]
  }
  atomicAdd(&sumR[i], sr);
  atomicAdd(&sumS[i], ss);
}

// Kernel C: single block, finalize per-row contributions and reduce to the
// two scalar losses. Runs after B completes (same stream ordering).
__global__ __launch_bounds__(1024) void ds_finalize(
    const float* __restrict__ Pr, const float* __restrict__ Ps,
    const int* __restrict__ E,
    const float* __restrict__ sumR, const float* __restrict__ sumS,
    float* __restrict__ out) {
  float nr = 0.0f, dr = 0.0f, ns = 0.0f, ds = 0.0f;
  for (int i = threadIdx.x; i < NN; i += 1024) {
    float srv = sumR[i];
    float ssv = sumS[i];
    float er = (E[i] != 0 && srv > 0.0f) ? 1.0f : 0.0f;
    float es = (ssv > 0.0f) ? 1.0f : 0.0f;
    nr += er * (Pr[i] - logf(srv + EPSF));
    dr += er;
    ns += es * (Ps[i] - logf(ssv + EPSF));
    ds += es;
  }
  // wave (64-lane) shuffle reduction
  for (int off = 32; off > 0; off >>= 1) {
    nr += __shfl_down(nr, off);
    dr += __shfl_down(dr, off);
    ns += __shfl_down(ns, off);
    ds += __shfl_down(ds, off);
  }
  __shared__ float sh[4][16];
  int wid  = threadIdx.x >> 6;
  int lane = threadIdx.x & 63;
  if (lane == 0) {
    sh[0][wid] = nr; sh[1][wid] = dr; sh[2][wid] = ns; sh[3][wid] = ds;
  }
  __syncthreads();
  if (threadIdx.x == 0) {
    float NR = 0, DR = 0, NS = 0, DS = 0;
#pragma unroll
    for (int w = 0; w < 16; ++w) {
      NR += sh[0][w]; DR += sh[1][w]; NS += sh[2][w]; DS += sh[3][w];
    }
    out[0] = -NR / DR;
    out[1] = -NS / DS;
  }
}

extern "C" void kernel_launch(void* const* d_in, const int* in_sizes, int n_in,
                              void* d_out, int out_size, void* d_ws, size_t ws_size,
                              hipStream_t stream) {
  const float* Pr = (const float*)d_in[0];
  const float* Ps = (const float*)d_in[1];
  const float* T  = (const float*)d_in[2];
  const int*   E  = (const int*)d_in[3];
  float* out = (float*)d_out;

  char* ws = (char*)d_ws;
  float4* pack = (float4*)ws;
  float*  sumR = (float*)(ws + (size_t)NN * sizeof(float4));
  float*  sumS = sumR + NN;

  ds_prep<<<NN / 256, 256, 0, stream>>>(Pr, Ps, T, E, pack, sumR, sumS);
  ds_main<<<dim3(NN / ROWS_PER_BLOCK, NN / J_CHUNK), 256, 0, stream>>>(T, pack, sumR, sumS);
  ds_finalize<<<1, 1024, 0, stream>>>(Pr, Ps, E, sumR, sumS, out);
}